// Round 7
// baseline (787.656 us; speedup 1.0000x reference)
//
#include <hip/hip_runtime.h>

// ---------------------------------------------------------------------------
// Swin Transformer block, MI355X gfx950.  fp32 I/O, bf16 MFMA internals.
// B=32 H=W=56 C=192 WS=7 SH=3 NH=6 HD=32 N=49 NW=64 HID=768
// R6: MLP v3 (parity double-buffered wave-private LDS + early w2 issue);
//     attn v2 (precomputed rpb-per-head bias, V^T staged in swizzled LDS).
// ---------------------------------------------------------------------------

typedef __bf16 bf16_t;
typedef __bf16 bf16x8 __attribute__((ext_vector_type(8)));
typedef float  f32x4  __attribute__((ext_vector_type(4)));

__device__ inline float wred_sum(float v) {
#pragma unroll
  for (int o = 32; o; o >>= 1) v += __shfl_xor(v, o);
  return v;
}

__device__ inline float gelu_tanh(float x) {
  float u = 0.7978845608028654f * (x + 0.044715f * x * x * x);
  float e = __expf(2.f * u);
  float t = 1.f - 2.f / (e + 1.f);   // tanh(u)
  return 0.5f * x * (1.f + t);
}

// ---------------------------------------------------------------------------
// K1: LN1 + roll(-3,-3) + window partition.  One wave per destination token.
// ---------------------------------------------------------------------------
__global__ __launch_bounds__(256) void k_ln1_win(
    const float* __restrict__ x, const float* __restrict__ sc,
    const float* __restrict__ bi, bf16_t* __restrict__ yw, int b0, int nTok) {
  int wv = (int)((blockIdx.x * 256 + threadIdx.x) >> 6);
  int lane = threadIdx.x & 63;
  if (wv >= nTok) return;
  int winL = wv / 49;
  int t = wv - winL * 49;
  int wi = winL & 63;
  int b = b0 + (winL >> 6);
  int t7 = t / 7;
  int hr = (wi >> 3) * 7 + t7;
  int wr = (wi & 7) * 7 + (t - t7 * 7);
  int h = hr + 3; if (h >= 56) h -= 56;
  int w = wr + 3; if (w >= 56) w -= 56;
  const float* xp = x + (((size_t)(b * 56 + h)) * 56 + w) * 192;
  float v0 = xp[lane], v1 = xp[lane + 64], v2 = xp[lane + 128];
  float s = wred_sum(v0 + v1 + v2);
  float q = wred_sum(v0 * v0 + v1 * v1 + v2 * v2);
  float mu = s * (1.f / 192.f);
  float var = q * (1.f / 192.f) - mu * mu;
  float rs = rsqrtf(var + 1e-6f);
  bf16_t* op = yw + (size_t)wv * 192;
  op[lane]       = (bf16_t)((v0 - mu) * rs * sc[lane]       + bi[lane]);
  op[lane + 64]  = (bf16_t)((v1 - mu) * rs * sc[lane + 64]  + bi[lane + 64]);
  op[lane + 128] = (bf16_t)((v2 - mu) * rs * sc[lane + 128] + bi[lane + 128]);
}

// ---------------------------------------------------------------------------
// K2: transpose + fp32->bf16.  out[n*K + k] = in[k*N + n]
// ---------------------------------------------------------------------------
__global__ __launch_bounds__(256) void k_transpose_cvt(
    const float* __restrict__ in, bf16_t* __restrict__ out, int K, int N) {
  int idx = blockIdx.x * 256 + threadIdx.x;
  if (idx >= K * N) return;
  int n = idx / K, k = idx - n * K;
  out[idx] = (bf16_t)in[(size_t)k * N + n];
}

// ---------------------------------------------------------------------------
// K2b: per-head relative position bias gather: rpbh[h*2401+n] = rpb[ri[n]*6+h]
// ---------------------------------------------------------------------------
__global__ __launch_bounds__(256) void k_rpb(
    const int* __restrict__ relidx, const float* __restrict__ rpb,
    float* __restrict__ rpbh) {
  int idx = blockIdx.x * 256 + threadIdx.x;
  if (idx >= 6 * 2401) return;
  int h = idx / 2401, n = idx - h * 2401;
  rpbh[idx] = rpb[relidx[n] * 6 + h];
}

// ---------------------------------------------------------------------------
// K3: B-stationary GEMM, zero barriers.  C[M][Nn] = A[M][K] @ Bt[Nn][K]^T + b
// ---------------------------------------------------------------------------
template <int K>
__global__ __launch_bounds__(256, 2) void k_gemm_bs(
    const bf16_t* __restrict__ A, const bf16_t* __restrict__ Bt,
    const float* __restrict__ bias, bf16_t* __restrict__ C, int Nn, int nMt) {
  constexpr int NKS = K / 32;
  int tid = threadIdx.x;
  int w = tid >> 6, lane = tid & 63;
  int c = lane & 15, g = lane >> 4;
  int bn = blockIdx.x;
  bf16x8 bf[4][NKS];
  const bf16_t* bp = Bt + (size_t)(bn * 64 + c) * K + 8 * g;
#pragma unroll
  for (int jc = 0; jc < 4; ++jc)
#pragma unroll
    for (int ks = 0; ks < NKS; ++ks)
      bf[jc][ks] = *(const bf16x8*)(bp + (size_t)jc * 16 * K + 32 * ks);
  float4 bias4[4];
#pragma unroll
  for (int jc = 0; jc < 4; ++jc)
    bias4[jc] = *(const float4*)(bias + bn * 64 + jc * 16 + 4 * g);
  for (int mt = blockIdx.y; mt < nMt; mt += gridDim.y) {
    int m0 = mt * 256 + w * 64;
    f32x4 acc[4][4] = {};  // [jc][ir]
    const bf16_t* ap = A + (size_t)(m0 + c) * K + 8 * g;
#pragma unroll
    for (int ks = 0; ks < NKS; ++ks) {
      bf16x8 af[4];
#pragma unroll
      for (int ir = 0; ir < 4; ++ir)
        af[ir] = *(const bf16x8*)(ap + (size_t)ir * 16 * K + 32 * ks);
#pragma unroll
      for (int jc = 0; jc < 4; ++jc)
#pragma unroll
        for (int ir = 0; ir < 4; ++ir)
          acc[jc][ir] = __builtin_amdgcn_mfma_f32_16x16x32_bf16(
              bf[jc][ks], af[ir], acc[jc][ir], 0, 0, 0);
    }
#pragma unroll
    for (int ir = 0; ir < 4; ++ir) {
      bf16_t* cp = C + (size_t)(m0 + ir * 16 + c) * Nn + bn * 64 + 4 * g;
#pragma unroll
      for (int jc = 0; jc < 4; ++jc) {
        union { uint2 u; bf16_t e[4]; } pk;
#pragma unroll
        for (int r = 0; r < 4; ++r)
          pk.e[r] = (bf16_t)(acc[jc][ir][r] + ((const float*)&bias4[jc])[r]);
        *(uint2*)(cp + jc * 16) = pk.u;
      }
    }
  }
}

// ---------------------------------------------------------------------------
// K4 (R6): windowed attention, one wave per (window, head).
// Bias from precomputed rpbh (two coalesced streams, no gather chain).
// V^T staged into 4KB XOR-swizzled LDS -> PV B-frags are 2x ds_read_b128
// instead of 32 scalar global gathers.  Single wave => no barriers.
// LDS: [0,8192) bias then P (sequential reuse), [8192,12288) V^T.
// ---------------------------------------------------------------------------
__global__ __launch_bounds__(64) void k_attn(
    const bf16_t* __restrict__ qkv, const float* __restrict__ rpbh,
    const float* __restrict__ mask, bf16_t* __restrict__ attn_out) {
  __shared__ char sm[12288];
  int blk = blockIdx.x;
  int wL = blk / 6, h = blk - wL * 6;
  int lane = threadIdx.x;
  int c = lane & 15, g = lane >> 4;
  const bf16_t* baseq = qkv + (size_t)wL * (49 * 576);

  // ---- bias: rpbh[h] + mask[wL&63], both coalesced
  {
    const float* mw = mask + (size_t)(wL & 63) * 2401;
    const float* bh = rpbh + (size_t)h * 2401;
    __bf16* bl = (__bf16*)sm;
    for (int idx = lane; idx < 2401; idx += 64)
      bl[idx] = (__bf16)(bh[idx] + mw[idx]);
  }

  // ---- stage V^T into vts[d=0..31][m=0..63] bf16, XOR-swizzled rows
  char* vts = sm + 8192;
  {
    uint4 z4 = {0u, 0u, 0u, 0u};
#pragma unroll
    for (int it = 0; it < 4; ++it)
      *(uint4*)(vts + lane * 16 + it * 1024) = z4;  // zero all 4KB (m>=49)
#pragma unroll
    for (int it = 0; it < 4; ++it) {
      int task = lane + 64 * it;  // 196 tasks: m x dchunk
      if (task < 196) {
        int m = task % 49, dc = task / 49;
        union { bf16x8 v; __bf16 e[8]; } u;
        u.v = *(const bf16x8*)(baseq + (size_t)m * 576 + 384 + h * 32 + dc * 8);
#pragma unroll
        for (int e0 = 0; e0 < 8; ++e0) {
          int d = dc * 8 + e0;
          *(__bf16*)(vts + d * 128 + ((2 * m) ^ ((d & 7) << 4))) = u.e[e0];
        }
      }
    }
  }

  // ---- S = Q K^T
  f32x4 s[4][4] = {};
  bf16x8 qf[4], kf[4];
#pragma unroll
  for (int i = 0; i < 4; ++i) {
    int n = c + 16 * i; if (n > 48) n = 48;
    qf[i] = *(const bf16x8*)(baseq + (size_t)n * 576 + h * 32 + g * 8);
  }
#pragma unroll
  for (int j = 0; j < 4; ++j) {
    int m = c + 16 * j; if (m > 48) m = 48;
    kf[j] = *(const bf16x8*)(baseq + (size_t)m * 576 + 192 + h * 32 + g * 8);
  }
#pragma unroll
  for (int i = 0; i < 4; ++i)
#pragma unroll
    for (int j = 0; j < 4; ++j)
      s[i][j] = __builtin_amdgcn_mfma_f32_16x16x32_bf16(qf[i], kf[j], s[i][j],
                                                        0, 0, 0);

  // ---- scale + bias + mask cols>=49; row max; softmax (unnormalized)
  const __bf16* bl = (const __bf16*)sm;
  float mxv[4][4], sum[4][4];
#pragma unroll
  for (int i = 0; i < 4; ++i)
#pragma unroll
    for (int r = 0; r < 4; ++r) {
      int n = 16 * i + 4 * g + r;
      int nc = n > 48 ? 48 : n;
      float best = -1e30f;
#pragma unroll
      for (int j = 0; j < 4; ++j) {
        int m = 16 * j + c;
        float v = -1e30f;
        if (m < 49)
          v = s[i][j][r] * 0.17677669529663687f + (float)bl[nc * 49 + m];
        s[i][j][r] = v;
        best = fmaxf(best, v);
      }
      mxv[i][r] = best;
    }
#pragma unroll
  for (int o = 8; o; o >>= 1)
#pragma unroll
    for (int i = 0; i < 4; ++i)
#pragma unroll
      for (int r = 0; r < 4; ++r)
        mxv[i][r] = fmaxf(mxv[i][r], __shfl_xor(mxv[i][r], o));
#pragma unroll
  for (int i = 0; i < 4; ++i)
#pragma unroll
    for (int r = 0; r < 4; ++r) {
      float ss = 0.f;
#pragma unroll
      for (int j = 0; j < 4; ++j) {
        float p = __expf(s[i][j][r] - mxv[i][r]);
        s[i][j][r] = p;
        ss += p;
      }
      sum[i][r] = ss;
    }
#pragma unroll
  for (int o = 8; o; o >>= 1)
#pragma unroll
    for (int i = 0; i < 4; ++i)
#pragma unroll
      for (int r = 0; r < 4; ++r)
        sum[i][r] += __shfl_xor(sum[i][r], o);

  // ---- P -> swizzled LDS (overwrites bias region; same-wave sequential)
#pragma unroll
  for (int i = 0; i < 4; ++i)
#pragma unroll
    for (int j = 0; j < 4; ++j)
#pragma unroll
      for (int r = 0; r < 4; ++r) {
        int n = 16 * i + 4 * g + r;
        int m = 16 * j + c;
        int offb = n * 128 + ((2 * m) ^ ((n & 7) << 4));
        *(__bf16*)(sm + offb) = (__bf16)s[i][j][r];
      }

  // ---- O = P V  (vf from V^T LDS)
  f32x4 o2[4][2] = {};
#pragma unroll
  for (int kt = 0; kt < 2; ++kt) {
    bf16x8 pf[4], vf[2];
#pragma unroll
    for (int i = 0; i < 4; ++i) {
      int n = c + 16 * i;
      int cb = (16 * g + 64 * kt) ^ ((n & 7) << 4);
      pf[i] = *(const bf16x8*)(sm + n * 128 + cb);
    }
#pragma unroll
    for (int dt = 0; dt < 2; ++dt) {
      int d = c + 16 * dt;
      vf[dt] = *(const bf16x8*)(vts + d * 128 +
                                ((64 * kt + 16 * g) ^ ((d & 7) << 4)));
    }
#pragma unroll
    for (int i = 0; i < 4; ++i)
#pragma unroll
      for (int dt = 0; dt < 2; ++dt)
        o2[i][dt] = __builtin_amdgcn_mfma_f32_16x16x32_bf16(pf[i], vf[dt],
                                                            o2[i][dt], 0, 0, 0);
  }

  // ---- epilogue, deferred 1/sum
#pragma unroll
  for (int i = 0; i < 4; ++i)
#pragma unroll
    for (int dt = 0; dt < 2; ++dt)
#pragma unroll
      for (int r = 0; r < 4; ++r) {
        int n = 16 * i + 4 * g + r;
        if (n < 49) {
          int d = 16 * dt + c;
          attn_out[((size_t)wL * 49 + n) * 192 + h * 32 + d] =
              (bf16_t)(o2[i][dt][r] / sum[i][r]);
        }
      }
}

// ---------------------------------------------------------------------------
// K6: window reverse + un-shift + residual -> d_out + LN2 -> z (bf16)
// ---------------------------------------------------------------------------
__global__ __launch_bounds__(256) void k_unwin_ln2(
    const float* __restrict__ x, const bf16_t* __restrict__ projw,
    const float* __restrict__ sc, const float* __restrict__ bi,
    float* __restrict__ out, bf16_t* __restrict__ z, int b0, int nTok) {
  int wv = (int)((blockIdx.x * 256 + threadIdx.x) >> 6);
  int lane = threadIdx.x & 63;
  if (wv >= nTok) return;
  int bL = wv / 3136;
  int rem = wv - bL * 3136;
  int hh = rem / 56, ww2 = rem - hh * 56;
  int b = b0 + bL;
  int hr = hh + 53; if (hr >= 56) hr -= 56;
  int wr = ww2 + 53; if (wr >= 56) wr -= 56;
  int winL = bL * 64 + (hr / 7) * 8 + (wr / 7);
  int t = (hr % 7) * 7 + (wr % 7);
  const bf16_t* pp = projw + ((size_t)winL * 49 + t) * 192;
  size_t gtok = ((size_t)(b * 56 + hh)) * 56 + ww2;
  const float* xp = x + gtok * 192;
  float v0 = xp[lane]       + (float)pp[lane];
  float v1 = xp[lane + 64]  + (float)pp[lane + 64];
  float v2 = xp[lane + 128] + (float)pp[lane + 128];
  float* op = out + gtok * 192;
  op[lane] = v0; op[lane + 64] = v1; op[lane + 128] = v2;
  float s = wred_sum(v0 + v1 + v2);
  float q = wred_sum(v0 * v0 + v1 * v1 + v2 * v2);
  float mu = s * (1.f / 192.f);
  float var = q * (1.f / 192.f) - mu * mu;
  float rs = rsqrtf(var + 1e-6f);
  bf16_t* zp = z + gtok * 192;
  zp[lane]       = (bf16_t)((v0 - mu) * rs * sc[lane]       + bi[lane]);
  zp[lane + 64]  = (bf16_t)((v1 - mu) * rs * sc[lane + 64]  + bi[lane + 64]);
  zp[lane + 128] = (bf16_t)((v2 - mu) * rs * sc[lane + 128] + bi[lane + 128]);
}

// ---------------------------------------------------------------------------
// K7 (R6): fused MLP v3.  out[m][192] += gelu(z @ w1 + b1) @ w2 + b2
// Wave-private 32 rows; hidden chunks via PARITY DOUBLE-BUFFERED wave-private
// LDS (hc&1 -> static after unroll 2, so no cross-iteration LDS false dep);
// w2 frags for ks2=0 issued right after gemm1 so L2 latency hides under
// gelu + LDS write.  Zero __syncthreads.
// ---------------------------------------------------------------------------
__global__ __launch_bounds__(256, 2) void k_mlp_fused3(
    const bf16_t* __restrict__ z, const bf16_t* __restrict__ w1T,
    const float* __restrict__ b1, const bf16_t* __restrict__ w2T,
    const float* __restrict__ b2, float* __restrict__ out) {
  __shared__ char hsm[32768];  // 4 waves x 2 buffers x 4KB
  int tid = threadIdx.x;
  int wv = tid >> 6, lane = tid & 63;
  int c = lane & 15, g = lane >> 4;
  char* wbase = hsm + wv * 8192;
  int row0 = blockIdx.x * 128 + wv * 32;

  bf16x8 zfr[2][6];
  const bf16_t* zp = z + (size_t)(row0 + c) * 192 + 8 * g;
#pragma unroll
  for (int ir = 0; ir < 2; ++ir)
#pragma unroll
    for (int ks = 0; ks < 6; ++ks)
      zfr[ir][ks] = *(const bf16x8*)(zp + (size_t)ir * 16 * 192 + 32 * ks);

  f32x4 acc2[12][2] = {};  // [jc][ir]: out col = jc*16+4g+r, row = 16ir+c

#pragma unroll 2
  for (int hc = 0; hc < 12; ++hc) {
    char* hbuf = wbase + (hc & 1) * 4096;
    // ---- gemm1: hidden chunk (64 cols) for this wave's 32 rows
    f32x4 acc1[4][2] = {};
    const bf16_t* w1p = w1T + (size_t)(hc * 64 + c) * 192 + 8 * g;
#pragma unroll
    for (int ks = 0; ks < 6; ++ks) {
      bf16x8 wf[4];
#pragma unroll
      for (int jh = 0; jh < 4; ++jh)
        wf[jh] = *(const bf16x8*)(w1p + (size_t)jh * 16 * 192 + 32 * ks);
#pragma unroll
      for (int jh = 0; jh < 4; ++jh)
#pragma unroll
        for (int ir = 0; ir < 2; ++ir)
          acc1[jh][ir] = __builtin_amdgcn_mfma_f32_16x16x32_bf16(
              wf[jh], zfr[ir][ks], acc1[jh][ir], 0, 0, 0);
    }
    // ---- early-issue w2 frags (ks2=0): latency hides under gelu+LDS below
    const bf16_t* w2p = w2T + (size_t)c * 768 + hc * 64 + 8 * g;
    bf16x8 wf2a[12];
#pragma unroll
    for (int jc = 0; jc < 12; ++jc)
      wf2a[jc] = *(const bf16x8*)(w2p + (size_t)jc * 16 * 768);
    // ---- bias + gelu -> bf16 -> parity LDS buffer
#pragma unroll
    for (int jh = 0; jh < 4; ++jh) {
      float4 b1v = *(const float4*)(b1 + hc * 64 + jh * 16 + 4 * g);
#pragma unroll
      for (int ir = 0; ir < 2; ++ir) {
        union { uint2 u; __bf16 e[4]; } pk;
#pragma unroll
        for (int r = 0; r < 4; ++r)
          pk.e[r] = (__bf16)gelu_tanh(acc1[jh][ir][r] + ((const float*)&b1v)[r]);
        int rl = ir * 16 + c;
        *(uint2*)(hbuf + rl * 128 + ((32 * jh + 8 * g) ^ ((rl & 7) << 4))) =
            pk.u;
      }
    }
    // ---- gemm2 ks2=0 (wf2a already in flight)
    {
      bf16x8 af[2];
#pragma unroll
      for (int ir = 0; ir < 2; ++ir) {
        int rl = ir * 16 + c;
        af[ir] = *(const bf16x8*)(hbuf + rl * 128 +
                                  ((16 * g) ^ ((rl & 7) << 4)));
      }
#pragma unroll
      for (int jc = 0; jc < 12; ++jc)
#pragma unroll
        for (int ir = 0; ir < 2; ++ir)
          acc2[jc][ir] = __builtin_amdgcn_mfma_f32_16x16x32_bf16(
              wf2a[jc], af[ir], acc2[jc][ir], 0, 0, 0);
    }
    // ---- gemm2 ks2=1
    {
      bf16x8 wf2b[12];
#pragma unroll
      for (int jc = 0; jc < 12; ++jc)
        wf2b[jc] = *(const bf16x8*)(w2p + (size_t)jc * 16 * 768 + 32);
      bf16x8 af[2];
#pragma unroll
      for (int ir = 0; ir < 2; ++ir) {
        int rl = ir * 16 + c;
        af[ir] = *(const bf16x8*)(hbuf + rl * 128 +
                                  ((64 + 16 * g) ^ ((rl & 7) << 4)));
      }
#pragma unroll
      for (int jc = 0; jc < 12; ++jc)
#pragma unroll
        for (int ir = 0; ir < 2; ++ir)
          acc2[jc][ir] = __builtin_amdgcn_mfma_f32_16x16x32_bf16(
              wf2b[jc], af[ir], acc2[jc][ir], 0, 0, 0);
    }
  }
  // ---- epilogue: float4 RMW + b2
#pragma unroll
  for (int jc = 0; jc < 12; ++jc) {
    float4 b2v = *(const float4*)(b2 + jc * 16 + 4 * g);
#pragma unroll
    for (int ir = 0; ir < 2; ++ir) {
      int row = row0 + ir * 16 + c;
      float* op = out + (size_t)row * 192 + jc * 16 + 4 * g;
      float4 cur = *(float4*)op;
      cur.x += acc2[jc][ir][0] + b2v.x;
      cur.y += acc2[jc][ir][1] + b2v.y;
      cur.z += acc2[jc][ir][2] + b2v.z;
      cur.w += acc2[jc][ir][3] + b2v.w;
      *(float4*)op = cur;
    }
  }
}

// ---------------------------------------------------------------------------
extern "C" void kernel_launch(void* const* d_in, const int* in_sizes, int n_in,
                              void* d_out, int out_size, void* d_ws,
                              size_t ws_size, hipStream_t stream) {
  (void)in_sizes; (void)n_in; (void)out_size;
  const float* x     = (const float*)d_in[0];
  const float* maskp = (const float*)d_in[1];
  const int*   reli  = (const int*)d_in[2];
  const float* ln1s  = (const float*)d_in[3];
  const float* ln1b  = (const float*)d_in[4];
  const float* qkvw  = (const float*)d_in[5];
  const float* qkvb  = (const float*)d_in[6];
  const float* rpb   = (const float*)d_in[7];
  const float* projw = (const float*)d_in[8];
  const float* projb = (const float*)d_in[9];
  const float* ln2s  = (const float*)d_in[10];
  const float* ln2b  = (const float*)d_in[11];
  const float* w1    = (const float*)d_in[12];
  const float* b1    = (const float*)d_in[13];
  const float* w2    = (const float*)d_in[14];
  const float* b2    = (const float*)d_in[15];
  float* out = (float*)d_out;

  auto aup = [](size_t v) { return (v + 255) & ~(size_t)255; };
  char* base = (char*)d_ws;
  size_t off = 0;
  bf16_t* z_buf = (bf16_t*)(base + off); off += aup((size_t)100352 * 192 * 2);
  bf16_t* qkvT  = (bf16_t*)(base + off); off += aup((size_t)576 * 192 * 2);
  bf16_t* projT = (bf16_t*)(base + off); off += aup((size_t)192 * 192 * 2);
  bf16_t* w1T   = (bf16_t*)(base + off); off += aup((size_t)768 * 192 * 2);
  bf16_t* w2T   = (bf16_t*)(base + off); off += aup((size_t)192 * 768 * 2);
  float*  rpbh  = (float*)(base + off);  off += aup((size_t)6 * 2401 * 4);
  size_t offB = off;

  int Bc = 32;  // batch chunk (multiple of 4 keeps M%256==0)
  while (Bc > 4 && offB + (size_t)Bc * 3136 * (576 + 192) * 2 > ws_size)
    Bc >>= 1;
  bf16_t* bufB = (bf16_t*)(base + offB);
  bf16_t* bufA = (bf16_t*)(base + offB + aup((size_t)Bc * 3136 * 576 * 2));

  k_transpose_cvt<<<(192 * 576 + 255) / 256, 256, 0, stream>>>(qkvw, qkvT, 192, 576);
  k_transpose_cvt<<<(192 * 192 + 255) / 256, 256, 0, stream>>>(projw, projT, 192, 192);
  k_transpose_cvt<<<(192 * 768 + 255) / 256, 256, 0, stream>>>(w1, w1T, 192, 768);
  k_transpose_cvt<<<(768 * 192 + 255) / 256, 256, 0, stream>>>(w2, w2T, 768, 192);
  k_rpb<<<(6 * 2401 + 255) / 256, 256, 0, stream>>>(reli, rpb, rpbh);

  for (int b0 = 0; b0 < 32; b0 += Bc) {
    int nTok = Bc * 3136, nWin = Bc * 64;
    int nMt = nTok / 256;
    k_ln1_win<<<nTok / 4, 256, 0, stream>>>(x, ln1s, ln1b, bufA, b0, nTok);
    {
      int nbn = 576 / 64;
      int gy = (512 + nbn - 1) / nbn; if (gy > nMt) gy = nMt;
      k_gemm_bs<192><<<dim3(nbn, gy), 256, 0, stream>>>(bufA, qkvT, qkvb, bufB,
                                                        576, nMt);
    }
    k_attn<<<nWin * 6, 64, 0, stream>>>(bufB, rpbh, maskp, bufA);
    {
      int nbn = 192 / 64;
      int gy = (512 + nbn - 1) / nbn; if (gy > nMt) gy = nMt;
      k_gemm_bs<192><<<dim3(nbn, gy), 256, 0, stream>>>(bufA, projT, projb,
                                                        bufB, 192, nMt);
    }
    k_unwin_ln2<<<nTok / 4, 256, 0, stream>>>(x, bufB, ln2s, ln2b, out, z_buf,
                                              b0, nTok);
  }

  k_mlp_fused3<<<100352 / 128, 256, 0, stream>>>(z_buf, w1T, b1, w2T, b2, out);
}

// Round 9
// 698.390 us; speedup vs baseline: 1.1278x; 1.1278x over previous
//
#include <hip/hip_runtime.h>

// ---------------------------------------------------------------------------
// Swin Transformer block, MI355X gfx950.  fp32 I/O, bf16 MFMA internals.
// B=32 H=W=56 C=192 WS=7 SH=3 NH=6 HD=32 N=49 NW=64 HID=768
// R8: MLP v4 — cooperative LDS weight staging (single-buffer 48KB, 2 blk/CU),
//     async stage-load/write split, wave-private hidden round-trip.
// R9: identical resubmit (R8 bench was a GPU-acquisition timeout, no data).
// ---------------------------------------------------------------------------

typedef __bf16 bf16_t;
typedef __bf16 bf16x8 __attribute__((ext_vector_type(8)));
typedef float  f32x4  __attribute__((ext_vector_type(4)));

__device__ inline float wred_sum(float v) {
#pragma unroll
  for (int o = 32; o; o >>= 1) v += __shfl_xor(v, o);
  return v;
}

__device__ inline float gelu_tanh(float x) {
  float u = 0.7978845608028654f * (x + 0.044715f * x * x * x);
  float e = __expf(2.f * u);
  float t = 1.f - 2.f / (e + 1.f);   // tanh(u)
  return 0.5f * x * (1.f + t);
}

// ---------------------------------------------------------------------------
// K1: LN1 + roll(-3,-3) + window partition.  One wave per destination token.
// ---------------------------------------------------------------------------
__global__ __launch_bounds__(256) void k_ln1_win(
    const float* __restrict__ x, const float* __restrict__ sc,
    const float* __restrict__ bi, bf16_t* __restrict__ yw, int b0, int nTok) {
  int wv = (int)((blockIdx.x * 256 + threadIdx.x) >> 6);
  int lane = threadIdx.x & 63;
  if (wv >= nTok) return;
  int winL = wv / 49;
  int t = wv - winL * 49;
  int wi = winL & 63;
  int b = b0 + (winL >> 6);
  int t7 = t / 7;
  int hr = (wi >> 3) * 7 + t7;
  int wr = (wi & 7) * 7 + (t - t7 * 7);
  int h = hr + 3; if (h >= 56) h -= 56;
  int w = wr + 3; if (w >= 56) w -= 56;
  const float* xp = x + (((size_t)(b * 56 + h)) * 56 + w) * 192;
  float v0 = xp[lane], v1 = xp[lane + 64], v2 = xp[lane + 128];
  float s = wred_sum(v0 + v1 + v2);
  float q = wred_sum(v0 * v0 + v1 * v1 + v2 * v2);
  float mu = s * (1.f / 192.f);
  float var = q * (1.f / 192.f) - mu * mu;
  float rs = rsqrtf(var + 1e-6f);
  bf16_t* op = yw + (size_t)wv * 192;
  op[lane]       = (bf16_t)((v0 - mu) * rs * sc[lane]       + bi[lane]);
  op[lane + 64]  = (bf16_t)((v1 - mu) * rs * sc[lane + 64]  + bi[lane + 64]);
  op[lane + 128] = (bf16_t)((v2 - mu) * rs * sc[lane + 128] + bi[lane + 128]);
}

// ---------------------------------------------------------------------------
// K2: transpose + fp32->bf16.  out[n*K + k] = in[k*N + n]
// ---------------------------------------------------------------------------
__global__ __launch_bounds__(256) void k_transpose_cvt(
    const float* __restrict__ in, bf16_t* __restrict__ out, int K, int N) {
  int idx = blockIdx.x * 256 + threadIdx.x;
  if (idx >= K * N) return;
  int n = idx / K, k = idx - n * K;
  out[idx] = (bf16_t)in[(size_t)k * N + n];
}

// ---------------------------------------------------------------------------
// K2b: per-head relative position bias gather: rpbh[h*2401+n] = rpb[ri[n]*6+h]
// ---------------------------------------------------------------------------
__global__ __launch_bounds__(256) void k_rpb(
    const int* __restrict__ relidx, const float* __restrict__ rpb,
    float* __restrict__ rpbh) {
  int idx = blockIdx.x * 256 + threadIdx.x;
  if (idx >= 6 * 2401) return;
  int h = idx / 2401, n = idx - h * 2401;
  rpbh[idx] = rpb[relidx[n] * 6 + h];
}

// ---------------------------------------------------------------------------
// K3: B-stationary GEMM, zero barriers.  C[M][Nn] = A[M][K] @ Bt[Nn][K]^T + b
// ---------------------------------------------------------------------------
template <int K>
__global__ __launch_bounds__(256, 2) void k_gemm_bs(
    const bf16_t* __restrict__ A, const bf16_t* __restrict__ Bt,
    const float* __restrict__ bias, bf16_t* __restrict__ C, int Nn, int nMt) {
  constexpr int NKS = K / 32;
  int tid = threadIdx.x;
  int w = tid >> 6, lane = tid & 63;
  int c = lane & 15, g = lane >> 4;
  int bn = blockIdx.x;
  bf16x8 bf[4][NKS];
  const bf16_t* bp = Bt + (size_t)(bn * 64 + c) * K + 8 * g;
#pragma unroll
  for (int jc = 0; jc < 4; ++jc)
#pragma unroll
    for (int ks = 0; ks < NKS; ++ks)
      bf[jc][ks] = *(const bf16x8*)(bp + (size_t)jc * 16 * K + 32 * ks);
  float4 bias4[4];
#pragma unroll
  for (int jc = 0; jc < 4; ++jc)
    bias4[jc] = *(const float4*)(bias + bn * 64 + jc * 16 + 4 * g);
  for (int mt = blockIdx.y; mt < nMt; mt += gridDim.y) {
    int m0 = mt * 256 + w * 64;
    f32x4 acc[4][4] = {};  // [jc][ir]
    const bf16_t* ap = A + (size_t)(m0 + c) * K + 8 * g;
#pragma unroll
    for (int ks = 0; ks < NKS; ++ks) {
      bf16x8 af[4];
#pragma unroll
      for (int ir = 0; ir < 4; ++ir)
        af[ir] = *(const bf16x8*)(ap + (size_t)ir * 16 * K + 32 * ks);
#pragma unroll
      for (int jc = 0; jc < 4; ++jc)
#pragma unroll
        for (int ir = 0; ir < 4; ++ir)
          acc[jc][ir] = __builtin_amdgcn_mfma_f32_16x16x32_bf16(
              bf[jc][ks], af[ir], acc[jc][ir], 0, 0, 0);
    }
#pragma unroll
    for (int ir = 0; ir < 4; ++ir) {
      bf16_t* cp = C + (size_t)(m0 + ir * 16 + c) * Nn + bn * 64 + 4 * g;
#pragma unroll
      for (int jc = 0; jc < 4; ++jc) {
        union { uint2 u; bf16_t e[4]; } pk;
#pragma unroll
        for (int r = 0; r < 4; ++r)
          pk.e[r] = (bf16_t)(acc[jc][ir][r] + ((const float*)&bias4[jc])[r]);
        *(uint2*)(cp + jc * 16) = pk.u;
      }
    }
  }
}

// ---------------------------------------------------------------------------
// K4: windowed attention, one wave per (window, head).  (R6 version)
// ---------------------------------------------------------------------------
__global__ __launch_bounds__(64) void k_attn(
    const bf16_t* __restrict__ qkv, const float* __restrict__ rpbh,
    const float* __restrict__ mask, bf16_t* __restrict__ attn_out) {
  __shared__ char sm[12288];
  int blk = blockIdx.x;
  int wL = blk / 6, h = blk - wL * 6;
  int lane = threadIdx.x;
  int c = lane & 15, g = lane >> 4;
  const bf16_t* baseq = qkv + (size_t)wL * (49 * 576);
  {
    const float* mw = mask + (size_t)(wL & 63) * 2401;
    const float* bh = rpbh + (size_t)h * 2401;
    __bf16* bl = (__bf16*)sm;
    for (int idx = lane; idx < 2401; idx += 64)
      bl[idx] = (__bf16)(bh[idx] + mw[idx]);
  }
  char* vts = sm + 8192;
  {
    uint4 z4 = {0u, 0u, 0u, 0u};
#pragma unroll
    for (int it = 0; it < 4; ++it)
      *(uint4*)(vts + lane * 16 + it * 1024) = z4;
#pragma unroll
    for (int it = 0; it < 4; ++it) {
      int task = lane + 64 * it;
      if (task < 196) {
        int m = task % 49, dc = task / 49;
        union { bf16x8 v; __bf16 e[8]; } u;
        u.v = *(const bf16x8*)(baseq + (size_t)m * 576 + 384 + h * 32 + dc * 8);
#pragma unroll
        for (int e0 = 0; e0 < 8; ++e0) {
          int d = dc * 8 + e0;
          *(__bf16*)(vts + d * 128 + ((2 * m) ^ ((d & 7) << 4))) = u.e[e0];
        }
      }
    }
  }
  f32x4 s[4][4] = {};
  bf16x8 qf[4], kf[4];
#pragma unroll
  for (int i = 0; i < 4; ++i) {
    int n = c + 16 * i; if (n > 48) n = 48;
    qf[i] = *(const bf16x8*)(baseq + (size_t)n * 576 + h * 32 + g * 8);
  }
#pragma unroll
  for (int j = 0; j < 4; ++j) {
    int m = c + 16 * j; if (m > 48) m = 48;
    kf[j] = *(const bf16x8*)(baseq + (size_t)m * 576 + 192 + h * 32 + g * 8);
  }
#pragma unroll
  for (int i = 0; i < 4; ++i)
#pragma unroll
    for (int j = 0; j < 4; ++j)
      s[i][j] = __builtin_amdgcn_mfma_f32_16x16x32_bf16(qf[i], kf[j], s[i][j],
                                                        0, 0, 0);
  const __bf16* bl = (const __bf16*)sm;
  float mxv[4][4], sum[4][4];
#pragma unroll
  for (int i = 0; i < 4; ++i)
#pragma unroll
    for (int r = 0; r < 4; ++r) {
      int n = 16 * i + 4 * g + r;
      int nc = n > 48 ? 48 : n;
      float best = -1e30f;
#pragma unroll
      for (int j = 0; j < 4; ++j) {
        int m = 16 * j + c;
        float v = -1e30f;
        if (m < 49)
          v = s[i][j][r] * 0.17677669529663687f + (float)bl[nc * 49 + m];
        s[i][j][r] = v;
        best = fmaxf(best, v);
      }
      mxv[i][r] = best;
    }
#pragma unroll
  for (int o = 8; o; o >>= 1)
#pragma unroll
    for (int i = 0; i < 4; ++i)
#pragma unroll
      for (int r = 0; r < 4; ++r)
        mxv[i][r] = fmaxf(mxv[i][r], __shfl_xor(mxv[i][r], o));
#pragma unroll
  for (int i = 0; i < 4; ++i)
#pragma unroll
    for (int r = 0; r < 4; ++r) {
      float ss = 0.f;
#pragma unroll
      for (int j = 0; j < 4; ++j) {
        float p = __expf(s[i][j][r] - mxv[i][r]);
        s[i][j][r] = p;
        ss += p;
      }
      sum[i][r] = ss;
    }
#pragma unroll
  for (int o = 8; o; o >>= 1)
#pragma unroll
    for (int i = 0; i < 4; ++i)
#pragma unroll
      for (int r = 0; r < 4; ++r)
        sum[i][r] += __shfl_xor(sum[i][r], o);
#pragma unroll
  for (int i = 0; i < 4; ++i)
#pragma unroll
    for (int j = 0; j < 4; ++j)
#pragma unroll
      for (int r = 0; r < 4; ++r) {
        int n = 16 * i + 4 * g + r;
        int m = 16 * j + c;
        int offb = n * 128 + ((2 * m) ^ ((n & 7) << 4));
        *(__bf16*)(sm + offb) = (__bf16)s[i][j][r];
      }
  f32x4 o2[4][2] = {};
#pragma unroll
  for (int kt = 0; kt < 2; ++kt) {
    bf16x8 pf[4], vf[2];
#pragma unroll
    for (int i = 0; i < 4; ++i) {
      int n = c + 16 * i;
      int cb = (16 * g + 64 * kt) ^ ((n & 7) << 4);
      pf[i] = *(const bf16x8*)(sm + n * 128 + cb);
    }
#pragma unroll
    for (int dt = 0; dt < 2; ++dt) {
      int d = c + 16 * dt;
      vf[dt] = *(const bf16x8*)(vts + d * 128 +
                                ((64 * kt + 16 * g) ^ ((d & 7) << 4)));
    }
#pragma unroll
    for (int i = 0; i < 4; ++i)
#pragma unroll
      for (int dt = 0; dt < 2; ++dt)
        o2[i][dt] = __builtin_amdgcn_mfma_f32_16x16x32_bf16(pf[i], vf[dt],
                                                            o2[i][dt], 0, 0, 0);
  }
#pragma unroll
  for (int i = 0; i < 4; ++i)
#pragma unroll
    for (int dt = 0; dt < 2; ++dt)
#pragma unroll
      for (int r = 0; r < 4; ++r) {
        int n = 16 * i + 4 * g + r;
        if (n < 49) {
          int d = 16 * dt + c;
          attn_out[((size_t)wL * 49 + n) * 192 + h * 32 + d] =
              (bf16_t)(o2[i][dt][r] / sum[i][r]);
        }
      }
}

// ---------------------------------------------------------------------------
// K6: window reverse + un-shift + residual -> d_out + LN2 -> z (bf16)
// ---------------------------------------------------------------------------
__global__ __launch_bounds__(256) void k_unwin_ln2(
    const float* __restrict__ x, const bf16_t* __restrict__ projw,
    const float* __restrict__ sc, const float* __restrict__ bi,
    float* __restrict__ out, bf16_t* __restrict__ z, int b0, int nTok) {
  int wv = (int)((blockIdx.x * 256 + threadIdx.x) >> 6);
  int lane = threadIdx.x & 63;
  if (wv >= nTok) return;
  int bL = wv / 3136;
  int rem = wv - bL * 3136;
  int hh = rem / 56, ww2 = rem - hh * 56;
  int b = b0 + bL;
  int hr = hh + 53; if (hr >= 56) hr -= 56;
  int wr = ww2 + 53; if (wr >= 56) wr -= 56;
  int winL = bL * 64 + (hr / 7) * 8 + (wr / 7);
  int t = (hr % 7) * 7 + (wr % 7);
  const bf16_t* pp = projw + ((size_t)winL * 49 + t) * 192;
  size_t gtok = ((size_t)(b * 56 + hh)) * 56 + ww2;
  const float* xp = x + gtok * 192;
  float v0 = xp[lane]       + (float)pp[lane];
  float v1 = xp[lane + 64]  + (float)pp[lane + 64];
  float v2 = xp[lane + 128] + (float)pp[lane + 128];
  float* op = out + gtok * 192;
  op[lane] = v0; op[lane + 64] = v1; op[lane + 128] = v2;
  float s = wred_sum(v0 + v1 + v2);
  float q = wred_sum(v0 * v0 + v1 * v1 + v2 * v2);
  float mu = s * (1.f / 192.f);
  float var = q * (1.f / 192.f) - mu * mu;
  float rs = rsqrtf(var + 1e-6f);
  bf16_t* zp = z + gtok * 192;
  zp[lane]       = (bf16_t)((v0 - mu) * rs * sc[lane]       + bi[lane]);
  zp[lane + 64]  = (bf16_t)((v1 - mu) * rs * sc[lane + 64]  + bi[lane + 64]);
  zp[lane + 128] = (bf16_t)((v2 - mu) * rs * sc[lane + 128] + bi[lane + 128]);
}

// ---------------------------------------------------------------------------
// K7 (R8): fused MLP v4.  out[m][192] += gelu(z @ w1 + b1) @ w2 + b2
// Block = 4 waves x 32 rows (128 rows).  Per 64-hcol chunk, weights are
// staged COOPERATIVELY into LDS once (reg-staged, XOR-swizzled), then all
// waves read fragments from LDS.  Stage loads for chunk hc+1 issue inside
// the gemm of chunk hc (T14 split: load-early / ds_write-late).
// LDS 64KB total -> 2 blocks/CU; 2 barriers per chunk hidden by co-residency.
// ---------------------------------------------------------------------------
__global__ __launch_bounds__(256, 2) void k_mlp_fused4(
    const bf16_t* __restrict__ z, const bf16_t* __restrict__ w1T,
    const float* __restrict__ b1, const bf16_t* __restrict__ w2T,
    const float* __restrict__ b2, float* __restrict__ out) {
  __shared__ char w1s[24576];   // [64 hcols][192 k] bf16, 384B/row, swizzled
  __shared__ char w2s[24576];   // [192 outcols][64 k] bf16, 128B/row, swizzled
  __shared__ char hsm[16384];   // 4 waves x 4KB wave-private hidden
  int tid = threadIdx.x;
  int wv = tid >> 6, lane = tid & 63;
  int c = lane & 15, g = lane >> 4;
  char* hbuf = hsm + wv * 4096;
  int row0 = blockIdx.x * 128 + wv * 32;

  // z tile in registers
  bf16x8 zfr[2][6];
  const bf16_t* zp = z + (size_t)(row0 + c) * 192 + 8 * g;
#pragma unroll
  for (int ir = 0; ir < 2; ++ir)
#pragma unroll
    for (int ks = 0; ks < 6; ++ks)
      zfr[ir][ks] = *(const bf16x8*)(zp + (size_t)ir * 16 * 192 + 32 * ks);

  // staging register buffers + per-thread task coords (6 x 16B per matrix)
  uint4 sv1[6], sv2[6];
  int r1[6], s1[6], r2[6], s2[6];
#pragma unroll
  for (int i = 0; i < 6; ++i) {
    int t = tid + 256 * i;
    r1[i] = t / 24; s1[i] = t - r1[i] * 24;   // w1: row=hcol(0..63), s=16B slot
    r2[i] = t >> 3; s2[i] = t & 7;            // w2: row=outcol(0..191), slot
  }
  // prologue: load chunk 0
#pragma unroll
  for (int i = 0; i < 6; ++i)
    sv1[i] = *(const uint4*)(w1T + (size_t)r1[i] * 192 + s1[i] * 8);
#pragma unroll
  for (int i = 0; i < 6; ++i)
    sv2[i] = *(const uint4*)(w2T + (size_t)r2[i] * 768 + s2[i] * 8);

  f32x4 acc2[12][2] = {};  // [jc][ir]: out col = jc*16+4g+r, row = 16ir+c

  for (int hc = 0; hc < 12; ++hc) {
    // ---- commit staged chunk hc to LDS (swizzled), make visible
#pragma unroll
    for (int i = 0; i < 6; ++i)
      *(uint4*)(w1s + r1[i] * 384 + ((s1[i] * 16) ^ ((r1[i] & 7) << 4))) =
          sv1[i];
#pragma unroll
    for (int i = 0; i < 6; ++i)
      *(uint4*)(w2s + r2[i] * 128 + ((s2[i] * 16) ^ ((r2[i] & 7) << 4))) =
          sv2[i];
    __syncthreads();
    // ---- issue stage loads for chunk hc+1 (land during gemm below)
    if (hc + 1 < 12) {
      const bf16_t* w1n = w1T + (size_t)(hc + 1) * 64 * 192;
#pragma unroll
      for (int i = 0; i < 6; ++i)
        sv1[i] = *(const uint4*)(w1n + (size_t)r1[i] * 192 + s1[i] * 8);
      const bf16_t* w2n = w2T + (size_t)(hc + 1) * 64;
#pragma unroll
      for (int i = 0; i < 6; ++i)
        sv2[i] = *(const uint4*)(w2n + (size_t)r2[i] * 768 + s2[i] * 8);
    }
    // ---- gemm1: acc1 = w1_chunk @ z  (frags from LDS)
    f32x4 acc1[4][2] = {};
#pragma unroll
    for (int ks = 0; ks < 6; ++ks) {
      bf16x8 wf[4];
#pragma unroll
      for (int jh = 0; jh < 4; ++jh) {
        int hcol = jh * 16 + c;
        wf[jh] = *(const bf16x8*)(w1s + hcol * 384 +
                                  ((64 * ks + 16 * g) ^ ((c & 7) << 4)));
      }
#pragma unroll
      for (int jh = 0; jh < 4; ++jh)
#pragma unroll
        for (int ir = 0; ir < 2; ++ir)
          acc1[jh][ir] = __builtin_amdgcn_mfma_f32_16x16x32_bf16(
              wf[jh], zfr[ir][ks], acc1[jh][ir], 0, 0, 0);
    }
    // ---- bias + gelu -> wave-private hidden LDS
#pragma unroll
    for (int jh = 0; jh < 4; ++jh) {
      float4 b1v = *(const float4*)(b1 + hc * 64 + jh * 16 + 4 * g);
#pragma unroll
      for (int ir = 0; ir < 2; ++ir) {
        union { uint2 u; __bf16 e[4]; } pk;
#pragma unroll
        for (int r = 0; r < 4; ++r)
          pk.e[r] = (__bf16)gelu_tanh(acc1[jh][ir][r] + ((const float*)&b1v)[r]);
        int rl = ir * 16 + c;
        *(uint2*)(hbuf + rl * 128 + ((32 * jh + 8 * g) ^ ((rl & 7) << 4))) =
            pk.u;
      }
    }
    // ---- gemm2: acc2 += h_chunk @ w2_chunk (both from LDS)
#pragma unroll
    for (int ks2 = 0; ks2 < 2; ++ks2) {
      bf16x8 af[2];
#pragma unroll
      for (int ir = 0; ir < 2; ++ir) {
        int rl = ir * 16 + c;
        af[ir] = *(const bf16x8*)(hbuf + rl * 128 +
                                  ((64 * ks2 + 16 * g) ^ ((rl & 7) << 4)));
      }
#pragma unroll
      for (int jc = 0; jc < 12; ++jc) {
        int oc = jc * 16 + c;
        bf16x8 wf2 = *(const bf16x8*)(w2s + oc * 128 +
                                      ((64 * ks2 + 16 * g) ^ ((c & 7) << 4)));
#pragma unroll
        for (int ir = 0; ir < 2; ++ir)
          acc2[jc][ir] = __builtin_amdgcn_mfma_f32_16x16x32_bf16(
              wf2, af[ir], acc2[jc][ir], 0, 0, 0);
      }
    }
    __syncthreads();  // all reads of w1s/w2s done; next iter may overwrite
  }
  // ---- epilogue: float4 RMW + b2
#pragma unroll
  for (int jc = 0; jc < 12; ++jc) {
    float4 b2v = *(const float4*)(b2 + jc * 16 + 4 * g);
#pragma unroll
    for (int ir = 0; ir < 2; ++ir) {
      int row = row0 + ir * 16 + c;
      float* op = out + (size_t)row * 192 + jc * 16 + 4 * g;
      float4 cur = *(float4*)op;
      cur.x += acc2[jc][ir][0] + b2v.x;
      cur.y += acc2[jc][ir][1] + b2v.y;
      cur.z += acc2[jc][ir][2] + b2v.z;
      cur.w += acc2[jc][ir][3] + b2v.w;
      *(float4*)op = cur;
    }
  }
}

// ---------------------------------------------------------------------------
extern "C" void kernel_launch(void* const* d_in, const int* in_sizes, int n_in,
                              void* d_out, int out_size, void* d_ws,
                              size_t ws_size, hipStream_t stream) {
  (void)in_sizes; (void)n_in; (void)out_size;
  const float* x     = (const float*)d_in[0];
  const float* maskp = (const float*)d_in[1];
  const int*   reli  = (const int*)d_in[2];
  const float* ln1s  = (const float*)d_in[3];
  const float* ln1b  = (const float*)d_in[4];
  const float* qkvw  = (const float*)d_in[5];
  const float* qkvb  = (const float*)d_in[6];
  const float* rpb   = (const float*)d_in[7];
  const float* projw = (const float*)d_in[8];
  const float* projb = (const float*)d_in[9];
  const float* ln2s  = (const float*)d_in[10];
  const float* ln2b  = (const float*)d_in[11];
  const float* w1    = (const float*)d_in[12];
  const float* b1    = (const float*)d_in[13];
  const float* w2    = (const float*)d_in[14];
  const float* b2    = (const float*)d_in[15];
  float* out = (float*)d_out;

  auto aup = [](size_t v) { return (v + 255) & ~(size_t)255; };
  char* base = (char*)d_ws;
  size_t off = 0;
  bf16_t* z_buf = (bf16_t*)(base + off); off += aup((size_t)100352 * 192 * 2);
  bf16_t* qkvT  = (bf16_t*)(base + off); off += aup((size_t)576 * 192 * 2);
  bf16_t* projT = (bf16_t*)(base + off); off += aup((size_t)192 * 192 * 2);
  bf16_t* w1T   = (bf16_t*)(base + off); off += aup((size_t)768 * 192 * 2);
  bf16_t* w2T   = (bf16_t*)(base + off); off += aup((size_t)192 * 768 * 2);
  float*  rpbh  = (float*)(base + off);  off += aup((size_t)6 * 2401 * 4);
  size_t offB = off;

  int Bc = 32;  // batch chunk (multiple of 4 keeps M%256==0)
  while (Bc > 4 && offB + (size_t)Bc * 3136 * (576 + 192) * 2 > ws_size)
    Bc >>= 1;
  bf16_t* bufB = (bf16_t*)(base + offB);
  bf16_t* bufA = (bf16_t*)(base + offB + aup((size_t)Bc * 3136 * 576 * 2));

  k_transpose_cvt<<<(192 * 576 + 255) / 256, 256, 0, stream>>>(qkvw, qkvT, 192, 576);
  k_transpose_cvt<<<(192 * 192 + 255) / 256, 256, 0, stream>>>(projw, projT, 192, 192);
  k_transpose_cvt<<<(192 * 768 + 255) / 256, 256, 0, stream>>>(w1, w1T, 192, 768);
  k_transpose_cvt<<<(768 * 192 + 255) / 256, 256, 0, stream>>>(w2, w2T, 768, 192);
  k_rpb<<<(6 * 2401 + 255) / 256, 256, 0, stream>>>(reli, rpb, rpbh);

  for (int b0 = 0; b0 < 32; b0 += Bc) {
    int nTok = Bc * 3136, nWin = Bc * 64;
    int nMt = nTok / 256;
    k_ln1_win<<<nTok / 4, 256, 0, stream>>>(x, ln1s, ln1b, bufA, b0, nTok);
    {
      int nbn = 576 / 64;
      int gy = (512 + nbn - 1) / nbn; if (gy > nMt) gy = nMt;
      k_gemm_bs<192><<<dim3(nbn, gy), 256, 0, stream>>>(bufA, qkvT, qkvb, bufB,
                                                        576, nMt);
    }
    k_attn<<<nWin * 6, 64, 0, stream>>>(bufB, rpbh, maskp, bufA);
    {
      int nbn = 192 / 64;
      int gy = (512 + nbn - 1) / nbn; if (gy > nMt) gy = nMt;
      k_gemm_bs<192><<<dim3(nbn, gy), 256, 0, stream>>>(bufA, projT, projb,
                                                        bufB, 192, nMt);
    }
    k_unwin_ln2<<<nTok / 4, 256, 0, stream>>>(x, bufB, ln2s, ln2b, out, z_buf,
                                              b0, nTok);
  }

  k_mlp_fused4<<<100352 / 128, 256, 0, stream>>>(z_buf, w1T, b1, w2T, b2, out);
}